// Round 1
// baseline (212.242 us; speedup 1.0000x reference)
//
#include <hip/hip_runtime.h>
#include <hip/hip_bf16.h>

// FocusAttention: B=8, L=S=1024, H=8, E=D=64
// qt = phi_p(q), kt = phi_p(k)  (power-norm p=2 over E)
// scores = qt @ kt^T per (b,h); A = softmax(fp(scores)) row-wise over S
//        = softmax(c * s^2) with c = sqrt(sum s^2)/sqrt(sum s^4)  (row consts)
// out = A @ v, output [B,L,H,D] fp32.
// Mask is all-False in this problem -> ignored.
//
// Design: c depends on the FULL score row -> online softmax impossible.
// Two passes over K per Q-block; recompute QK^T in pass 2 (ws stays 40MB).
// Pass 2 uses split-bf16 (hi+lo) QK^T: softmax here is very peaked
// (c*M ~ 34), plain bf16 score noise (~0.4%) would shift near-tied top
// weights by ~7% -> absmax ~0.1-0.2 > threshold. Split path -> ~1e-3.

#define B_ 8
#define L_ 1024
#define H_ 8
#define E_ 64
#define S_ 1024
#define D_ 64
#define BH_ (B_*H_)

typedef __bf16 bf16_t;
typedef __bf16 bf16x8 __attribute__((ext_vector_type(8)));
typedef float f32x4 __attribute__((ext_vector_type(4)));

#define MFMA16(a, b, c) __builtin_amdgcn_mfma_f32_16x16x32_bf16(a, b, c, 0, 0, 0)

__device__ __forceinline__ float wave64_sum(float v) {
#pragma unroll
  for (int off = 32; off > 0; off >>= 1) v += __shfl_xor(v, off, 64);
  return v;
}

// ---------------------------------------------------------------------------
// K1: phi_p for q and k rows (64 elems/row, one wave per row).
// Writes hi/lo bf16 split into [B,H,L,E] layout.
// ---------------------------------------------------------------------------
__global__ __launch_bounds__(256) void phi_kernel(
    const float* __restrict__ q, const float* __restrict__ k,
    bf16_t* __restrict__ qh, bf16_t* __restrict__ ql,
    bf16_t* __restrict__ kh, bf16_t* __restrict__ kl) {
  int row = blockIdx.x * 4 + (threadIdx.x >> 6);
  int lane = threadIdx.x & 63;
  const float* src;
  bf16_t *dh, *dl;
  int r = row;
  if (r < B_ * L_ * H_) { src = q; dh = qh; dl = ql; }
  else { r -= B_ * L_ * H_; src = k; dh = kh; dl = kl; }
  int b = r >> 13;            // r / (L*H)
  int l = (r >> 3) & 1023;
  int h = r & 7;
  float x = src[(size_t)r * 64 + lane];
  float rl = fmaxf(x, 0.f);
  float s2 = rl * rl;
  float sum2 = wave64_sum(s2);
  float sum4 = wave64_sum(s2 * s2);
  // norm*x^2/pnorm = sqrt(sum2/sum4)*x^2 ; guard all-zero row (ref would NaN,
  // probability ~2^-64 with random normal inputs)
  float val = (sum4 > 0.f) ? (sqrtf(sum2 / sum4) * s2) : 0.f;
  bf16_t hi = (bf16_t)val;
  bf16_t lo = (bf16_t)(val - (float)hi);
  size_t o = ((size_t)(b * H_ + h) * 1024 + l) * 64 + lane;
  dh[o] = hi;
  dl[o] = lo;
}

// ---------------------------------------------------------------------------
// K1b: V [B,S,H,D] fp32 -> Vt [B,H,D,S] bf16 (transposed for PV B-operand)
// ---------------------------------------------------------------------------
__global__ __launch_bounds__(256) void vt_kernel(
    const float* __restrict__ v, bf16_t* __restrict__ vt) {
  __shared__ float tile[64][65];
  int bh = blockIdx.x >> 4;
  int st = blockIdx.x & 15;
  int b = bh >> 3, h = bh & 7;
  int t = threadIdx.x;
  int r = t >> 2, cc = t & 3;
  const float* src = v + (((size_t)(b * S_ + st * 64 + r) * H_ + h) * D_) + cc * 16;
#pragma unroll
  for (int i = 0; i < 4; ++i) {
    float4 f = ((const float4*)src)[i];
    tile[r][cc * 16 + i * 4 + 0] = f.x;
    tile[r][cc * 16 + i * 4 + 1] = f.y;
    tile[r][cc * 16 + i * 4 + 2] = f.z;
    tile[r][cc * 16 + i * 4 + 3] = f.w;
  }
  __syncthreads();
  bf16_t* dst = vt + ((size_t)bh * D_ + r) * S_ + st * 64 + cc * 16;
#pragma unroll
  for (int j = 0; j < 16; ++j) dst[j] = (bf16_t)tile[cc * 16 + j][r];
}

// ---------------------------------------------------------------------------
// K2: fused two-pass attention. One block = (b,h) x 64 q-rows; 4 waves x 16.
// Pass 1: single-bf16 QK^T -> row stats (sum s^2, sum s^4, max s^2).
// Pass 2: split-bf16 QK^T -> w = exp(c*s^2 - c*M) -> LDS A-layout -> PV MFMA.
// MFMA layouts (m89/m91-verified): C/D col=lane&15, row=(lane>>4)*4+reg;
// A[m=lane&15][k=(lane>>4)*8+j]; B[k=(lane>>4)*8+j][n=lane&15].
// ---------------------------------------------------------------------------
__global__ __launch_bounds__(256, 2) void attn_kernel(
    const bf16_t* __restrict__ qh, const bf16_t* __restrict__ ql,
    const bf16_t* __restrict__ kh, const bf16_t* __restrict__ kl,
    const bf16_t* __restrict__ vt, float* __restrict__ out) {
  constexpr int PAD = 72;  // 144B rows: 16B-aligned, 2-way-max bank aliasing
  __shared__ __align__(16) bf16_t qtile_h[64 * PAD];
  __shared__ __align__(16) bf16_t qtile_l[64 * PAD];
  __shared__ __align__(16) bf16_t ktile_h[64 * PAD];
  __shared__ __align__(16) bf16_t ktile_l[64 * PAD];
  __shared__ __align__(16) bf16_t vtile[64 * PAD];
  __shared__ __align__(16) bf16_t wbuf[4 * 16 * PAD];  // per-wave w tiles

  int bh = blockIdx.x >> 4;
  int qb = blockIdx.x & 15;
  int b = bh >> 3, h = bh & 7;
  int tid = threadIdx.x;
  int wave = tid >> 6, lane = tid & 63;
  int g = lane >> 4, n = lane & 15;

  const bf16_t* qh_b = qh + ((size_t)bh * L_ + qb * 64) * E_;
  const bf16_t* ql_b = ql + ((size_t)bh * L_ + qb * 64) * E_;
  const bf16_t* kh_b = kh + (size_t)bh * S_ * E_;
  const bf16_t* kl_b = kl + (size_t)bh * S_ * E_;
  const bf16_t* vt_b = vt + (size_t)bh * D_ * S_;

  const f32x4 fzero = {0.f, 0.f, 0.f, 0.f};

  // stage q tiles (64x64 bf16 each): 256 thr x 2 x 16B
#pragma unroll
  for (int i = 0; i < 2; ++i) {
    int id = tid * 2 + i;
    int row = id >> 3, ch = id & 7;
    *(uint4*)&qtile_h[row * PAD + ch * 8] = *(const uint4*)&qh_b[row * 64 + ch * 8];
    *(uint4*)&qtile_l[row * PAD + ch * 8] = *(const uint4*)&ql_b[row * 64 + ch * 8];
  }
  __syncthreads();

  // A-fragments of q are loop-invariant: preload (2 k-steps, hi+lo)
  int arow = wave * 16 + n;
  bf16x8 qah0 = *(const bf16x8*)&qtile_h[arow * PAD + g * 8];
  bf16x8 qah1 = *(const bf16x8*)&qtile_h[arow * PAD + 32 + g * 8];
  bf16x8 qal0 = *(const bf16x8*)&qtile_l[arow * PAD + g * 8];
  bf16x8 qal1 = *(const bf16x8*)&qtile_l[arow * PAD + 32 + g * 8];

  float acc2[4] = {0, 0, 0, 0}, acc4[4] = {0, 0, 0, 0}, mx[4] = {0, 0, 0, 0};

  // ---- PASS 1: stats ----
  for (int stile = 0; stile < 16; ++stile) {
    __syncthreads();
#pragma unroll
    for (int i = 0; i < 2; ++i) {
      int id = tid * 2 + i;
      int row = id >> 3, ch = id & 7;
      *(uint4*)&ktile_h[row * PAD + ch * 8] =
          *(const uint4*)&kh_b[(stile * 64 + row) * 64 + ch * 8];
    }
    __syncthreads();
    f32x4 sc[4];
#pragma unroll
    for (int cg = 0; cg < 4; ++cg) {
      sc[cg] = fzero;
      bf16x8 b0 = *(const bf16x8*)&ktile_h[(cg * 16 + n) * PAD + g * 8];
      bf16x8 b1 = *(const bf16x8*)&ktile_h[(cg * 16 + n) * PAD + 32 + g * 8];
      sc[cg] = MFMA16(qah0, b0, sc[cg]);
      sc[cg] = MFMA16(qah1, b1, sc[cg]);
    }
#pragma unroll
    for (int cg = 0; cg < 4; ++cg)
#pragma unroll
      for (int r = 0; r < 4; ++r) {
        float s = sc[cg][r];
        float s2 = s * s;
        acc2[r] += s2;
        acc4[r] = fmaf(s2, s2, acc4[r]);
        mx[r] = fmaxf(mx[r], s2);
      }
  }
  // reduce row stats across the 16 lanes holding each row's columns
#pragma unroll
  for (int off = 1; off < 16; off <<= 1)
#pragma unroll
    for (int r = 0; r < 4; ++r) {
      acc2[r] += __shfl_xor(acc2[r], off, 64);
      acc4[r] += __shfl_xor(acc4[r], off, 64);
      mx[r] = fmaxf(mx[r], __shfl_xor(mx[r], off, 64));
    }
  float cr[4], cm[4];
#pragma unroll
  for (int r = 0; r < 4; ++r) {
    cr[r] = (acc4[r] > 0.f) ? sqrtf(acc2[r] / acc4[r]) : 0.f;
    cm[r] = cr[r] * mx[r];
  }

  f32x4 pv[4];
#pragma unroll
  for (int dg = 0; dg < 4; ++dg) pv[dg] = fzero;
  float den[4] = {0, 0, 0, 0};
  bf16_t* wb = &wbuf[wave * 16 * PAD];

  // ---- PASS 2: weights + PV ----
  for (int stile = 0; stile < 16; ++stile) {
    __syncthreads();
#pragma unroll
    for (int i = 0; i < 2; ++i) {
      int id = tid * 2 + i;
      int row = id >> 3, ch = id & 7;
      int go = (stile * 64 + row) * 64 + ch * 8;
      *(uint4*)&ktile_h[row * PAD + ch * 8] = *(const uint4*)&kh_b[go];
      *(uint4*)&ktile_l[row * PAD + ch * 8] = *(const uint4*)&kl_b[go];
      *(uint4*)&vtile[row * PAD + ch * 8] =
          *(const uint4*)&vt_b[row * S_ + stile * 64 + ch * 8];
    }
    __syncthreads();
    f32x4 sc[4];
#pragma unroll
    for (int cg = 0; cg < 4; ++cg) {
      sc[cg] = fzero;
      bf16x8 bh0 = *(const bf16x8*)&ktile_h[(cg * 16 + n) * PAD + g * 8];
      bf16x8 bh1 = *(const bf16x8*)&ktile_h[(cg * 16 + n) * PAD + 32 + g * 8];
      bf16x8 bl0 = *(const bf16x8*)&ktile_l[(cg * 16 + n) * PAD + g * 8];
      bf16x8 bl1 = *(const bf16x8*)&ktile_l[(cg * 16 + n) * PAD + 32 + g * 8];
      // split product: qh*kh + qh*kl + ql*kh (ql*kl negligible)
      sc[cg] = MFMA16(qah0, bh0, sc[cg]);
      sc[cg] = MFMA16(qah1, bh1, sc[cg]);
      sc[cg] = MFMA16(qah0, bl0, sc[cg]);
      sc[cg] = MFMA16(qah1, bl1, sc[cg]);
      sc[cg] = MFMA16(qal0, bh0, sc[cg]);
      sc[cg] = MFMA16(qal1, bh1, sc[cg]);
    }
    // w = exp(c*s^2 - c*M); stash to LDS (C-layout -> A-layout transform)
#pragma unroll
    for (int cg = 0; cg < 4; ++cg)
#pragma unroll
      for (int r = 0; r < 4; ++r) {
        float s = sc[cg][r];
        float w = __expf(fmaf(cr[r], s * s, -cm[r]));
        den[r] += w;
        wb[(g * 4 + r) * PAD + cg * 16 + n] = (bf16_t)w;
      }
    // wave-local write->read: LDS ops in-order within a wave
    bf16x8 wa0 = *(const bf16x8*)&wb[n * PAD + g * 8];
    bf16x8 wa1 = *(const bf16x8*)&wb[n * PAD + 32 + g * 8];
#pragma unroll
    for (int dg = 0; dg < 4; ++dg) {
      bf16x8 vb0 = *(const bf16x8*)&vtile[(dg * 16 + n) * PAD + g * 8];
      bf16x8 vb1 = *(const bf16x8*)&vtile[(dg * 16 + n) * PAD + 32 + g * 8];
      pv[dg] = MFMA16(wa0, vb0, pv[dg]);
      pv[dg] = MFMA16(wa1, vb1, pv[dg]);
    }
  }
  // denominator reduce + normalize + store [B,L,H,D]
#pragma unroll
  for (int off = 1; off < 16; off <<= 1)
#pragma unroll
    for (int r = 0; r < 4; ++r) den[r] += __shfl_xor(den[r], off, 64);
#pragma unroll
  for (int r = 0; r < 4; ++r) {
    float inv = 1.f / den[r];
    int l = qb * 64 + wave * 16 + g * 4 + r;
    float* op = out + (((size_t)b * L_ + l) * H_ + h) * D_;
#pragma unroll
    for (int dg = 0; dg < 4; ++dg) op[dg * 16 + n] = pv[dg][r] * inv;
  }
}

extern "C" void kernel_launch(void* const* d_in, const int* in_sizes, int n_in,
                              void* d_out, int out_size, void* d_ws, size_t ws_size,
                              hipStream_t stream) {
  const float* q = (const float*)d_in[0];
  const float* k = (const float*)d_in[1];
  const float* v = (const float*)d_in[2];
  // d_in[3] (attn_mask) is all-False -> unused
  float* out = (float*)d_out;

  const size_t NE = (size_t)B_ * L_ * H_ * E_;  // 4,194,304 elems
  bf16_t* qh = (bf16_t*)d_ws;                   // ws usage: 5*NE*2B = 40 MB
  bf16_t* ql = qh + NE;
  bf16_t* kh = ql + NE;
  bf16_t* kl = kh + NE;
  bf16_t* vt = kl + NE;

  phi_kernel<<<(2 * B_ * L_ * H_) / 4, 256, 0, stream>>>(q, k, qh, ql, kh, kl);
  vt_kernel<<<BH_ * (S_ / 64), 256, 0, stream>>>(v, vt);
  attn_kernel<<<BH_ * (L_ / 64), 256, 0, stream>>>(qh, ql, kh, kl, vt, out);
}

// Round 2
// 201.284 us; speedup vs baseline: 1.0544x; 1.0544x over previous
//
#include <hip/hip_runtime.h>
#include <hip/hip_bf16.h>

// FocusAttention: B=8, L=S=1024, H=8, E=D=64
// qt = phi_p(q), kt = phi_p(k)  (power-norm p=2 over E)
// A = softmax(c * s^2) rowwise, c = sqrt(sum s^2 / sum s^4) (full-row const
// -> online softmax impossible; two passes over K, recompute QK^T in pass 2
// with split-bf16 hi+lo for score precision; see round-1 notes).
// out = A @ v, [B,L,H,D] fp32.
//
// R2: latency/occupancy restructure. R1 counters: Occ 20%, Mfma 18%, VALU 25%
// -> barrier-latency bound at 2 blocks/CU (54KB LDS). Changes:
//  - Q fragments direct from global (q tiles out of LDS)
//  - 32-row K tiles, double-buffered, staged via global_load_lds (16B),
//    ONE barrier per tile, loads for t+1 in flight during compute of t
//  - glds needs lane-linear LDS -> XOR chunk-swizzle pre-applied in GLOBAL
//    layout (phi writes chunk c at position c^(row&7)); B-frag reads then
//    hit 8 lanes x 4 words per 4-bank group = balanced (min phases)
//  - vt stored as [bh][32 s-tiles][64 d][32 s] so v staging is contiguous

#define B_ 8
#define L_ 1024
#define H_ 8
#define E_ 64
#define S_ 1024
#define D_ 64
#define BH_ 64

typedef __bf16 bf16_t;
typedef __bf16 bf16x8 __attribute__((ext_vector_type(8)));
typedef float f32x4 __attribute__((ext_vector_type(4)));

#define MFMA16(a, b, c) __builtin_amdgcn_mfma_f32_16x16x32_bf16(a, b, c, 0, 0, 0)
#define GLDS16(g, l)                                                        \
  __builtin_amdgcn_global_load_lds(                                         \
      (const __attribute__((address_space(1))) void*)(g),                   \
      (__attribute__((address_space(3))) void*)(l), 16, 0, 0)

__device__ __forceinline__ float wave64_sum(float v) {
#pragma unroll
  for (int off = 32; off > 0; off >>= 1) v += __shfl_xor(v, off, 64);
  return v;
}

// ---------------------------------------------------------------------------
// K1: phi_p rows (one wave per 64-elem row) -> hi/lo bf16 in [B,H,row,E]
// with XOR chunk swizzle: chunk c (8 elems) stored at position c^(row&7).
// ---------------------------------------------------------------------------
__global__ __launch_bounds__(256) void phi_kernel(
    const float* __restrict__ q, const float* __restrict__ k,
    bf16_t* __restrict__ qh, bf16_t* __restrict__ ql,
    bf16_t* __restrict__ kh, bf16_t* __restrict__ kl) {
  int row = blockIdx.x * 4 + (threadIdx.x >> 6);
  int lane = threadIdx.x & 63;
  const float* src;
  bf16_t *dh, *dl;
  int r = row;
  if (r < B_ * L_ * H_) { src = q; dh = qh; dl = ql; }
  else { r -= B_ * L_ * H_; src = k; dh = kh; dl = kl; }
  int b = r >> 13;            // r / (L*H)
  int l = (r >> 3) & 1023;
  int h = r & 7;
  float x = src[(size_t)r * 64 + lane];
  float rl = fmaxf(x, 0.f);
  float s2 = rl * rl;
  float sum2 = wave64_sum(s2);
  float sum4 = wave64_sum(s2 * s2);
  float val = (sum4 > 0.f) ? (sqrtf(sum2 / sum4) * s2) : 0.f;
  bf16_t hi = (bf16_t)val;
  bf16_t lo = (bf16_t)(val - (float)hi);
  int c = lane >> 3, e = lane & 7;
  int col = ((c ^ (l & 7)) << 3) | e;  // swizzled chunk position
  size_t o = ((size_t)(b * H_ + h) * 1024 + l) * 64 + col;
  dh[o] = hi;
  dl[o] = lo;
}

// ---------------------------------------------------------------------------
// K1b: V [B,S,H,D] fp32 -> vt bf16 tiled [bh][st=S/32][64 d][32 s]
// (so attn's v staging is a contiguous 4KB block per tile)
// ---------------------------------------------------------------------------
__global__ __launch_bounds__(256) void vt_kernel(
    const float* __restrict__ v, bf16_t* __restrict__ vt) {
  __shared__ float tile[32][68];
  int bh = blockIdx.x >> 5;
  int st = blockIdx.x & 31;
  int b = bh >> 3, h = bh & 7;
  int t = threadIdx.x;
  int sl = t >> 3, dp = t & 7;
  const float* src = v + (((size_t)(b * S_ + st * 32 + sl) * H_ + h) * D_) + dp * 8;
  float4 f0 = ((const float4*)src)[0];
  float4 f1 = ((const float4*)src)[1];
  *(float4*)&tile[sl][dp * 8] = f0;
  *(float4*)&tile[sl][dp * 8 + 4] = f1;
  __syncthreads();
  int d = t >> 2, sc = t & 3;
  bf16_t tmp[8];
#pragma unroll
  for (int j = 0; j < 8; ++j) tmp[j] = (bf16_t)tile[sc * 8 + j][d];
  bf16_t* dst = vt + (((size_t)bh * 32 + st) * 64 + d) * 32 + sc * 8;
  *(uint4*)dst = *(const uint4*)tmp;
}

// ---------------------------------------------------------------------------
// K2: fused two-pass attention. Block = (b,h) x 64 q-rows; 4 waves x 16 rows.
// 32-row K tiles, double-buffered glds staging, 1 barrier/tile.
// MFMA layouts (m89/m91): C/D col=lane&15, row=(lane>>4)*4+reg;
// A[m=lane&15][k=(lane>>4)*8+j]; B[k=(lane>>4)*8+j][n=lane&15].
// ---------------------------------------------------------------------------
__global__ __launch_bounds__(256, 4) void attn_kernel(
    const bf16_t* __restrict__ qh, const bf16_t* __restrict__ ql,
    const bf16_t* __restrict__ kh, const bf16_t* __restrict__ kl,
    const bf16_t* __restrict__ vt, float* __restrict__ out) {
  __shared__ __align__(16) bf16_t kh_t[2][2048];  // 32 s-rows x 64 e (swizzled)
  __shared__ __align__(16) bf16_t kl_t[2][2048];
  __shared__ __align__(16) bf16_t v_t[2][2048];   // 64 d-rows x 32 s (linear)
  __shared__ __align__(16) bf16_t wbuf[4][16 * 40];  // per-wave w, PAD 40

  int bh = blockIdx.x >> 4;
  int qb = blockIdx.x & 15;
  int b = bh >> 3, h = bh & 7;
  int tid = threadIdx.x;
  int wave = tid >> 6, lane = tid & 63;
  int g = lane >> 4, n = lane & 15;

  const bf16_t* qh_b = qh + ((size_t)bh * L_ + qb * 64) * 64;
  const bf16_t* ql_b = ql + ((size_t)bh * L_ + qb * 64) * 64;
  const bf16_t* kh_b = kh + (size_t)bh * S_ * 64;
  const bf16_t* kl_b = kl + (size_t)bh * S_ * 64;
  const bf16_t* vt_b = vt + (size_t)bh * 32 * 2048;

  // Q A-fragments straight from global (swizzled chunk addressing).
  // chunk for k-step 0 is g, for k-step 1 is g+4 = g^4 -> offset ^32.
  int arow = wave * 16 + n;
  int qoff = arow * 64 + ((g ^ (n & 7)) << 3);
  bf16x8 qah0 = *(const bf16x8*)(qh_b + qoff);
  bf16x8 qah1 = *(const bf16x8*)(qh_b + (qoff ^ 32));
  bf16x8 qal0 = *(const bf16x8*)(ql_b + qoff);
  bf16x8 qal1 = *(const bf16x8*)(ql_b + (qoff ^ 32));

  // B-fragment base offset within a k tile (row n; row n+16 is +1024)
  int koff = n * 64 + ((g ^ (n & 7)) << 3);
  int lds_o = tid * 8;  // lane-linear staging slot (16B/thread)

  const f32x4 fzero = {0.f, 0.f, 0.f, 0.f};
  float acc2[4] = {0, 0, 0, 0}, acc4[4] = {0, 0, 0, 0}, mx[4] = {0, 0, 0, 0};

  // ---- PASS 1: row stats (single-bf16 scores suffice; c only shifts
  // near-tied exponents by ~1e-3, M cancels in softmax) ----
  GLDS16(kh_b + lds_o, &kh_t[0][lds_o]);
  for (int t = 0; t < 32; ++t) {
    __syncthreads();  // drains this wave's glds; barrier => tile t ready
    if (t < 31) GLDS16(kh_b + (t + 1) * 2048 + lds_o, &kh_t[(t + 1) & 1][lds_o]);
    const bf16_t* kt = kh_t[t & 1];
    bf16x8 b00 = *(const bf16x8*)(kt + koff);
    bf16x8 b01 = *(const bf16x8*)(kt + (koff ^ 32));
    bf16x8 b10 = *(const bf16x8*)(kt + koff + 1024);
    bf16x8 b11 = *(const bf16x8*)(kt + (koff ^ 32) + 1024);
    f32x4 sc0 = fzero, sc1 = fzero;
    sc0 = MFMA16(qah0, b00, sc0);
    sc0 = MFMA16(qah1, b01, sc0);
    sc1 = MFMA16(qah0, b10, sc1);
    sc1 = MFMA16(qah1, b11, sc1);
#pragma unroll
    for (int r = 0; r < 4; ++r) {
      float s = sc0[r], s2 = s * s;
      acc2[r] += s2; acc4[r] = fmaf(s2, s2, acc4[r]); mx[r] = fmaxf(mx[r], s2);
      s = sc1[r]; s2 = s * s;
      acc2[r] += s2; acc4[r] = fmaf(s2, s2, acc4[r]); mx[r] = fmaxf(mx[r], s2);
    }
  }
#pragma unroll
  for (int off = 1; off < 16; off <<= 1)
#pragma unroll
    for (int r = 0; r < 4; ++r) {
      acc2[r] += __shfl_xor(acc2[r], off, 64);
      acc4[r] += __shfl_xor(acc4[r], off, 64);
      mx[r] = fmaxf(mx[r], __shfl_xor(mx[r], off, 64));
    }
  float c2[4], cm2[4];
  const float LOG2E = 1.44269504f;
#pragma unroll
  for (int r = 0; r < 4; ++r) {
    float cr = (acc4[r] > 0.f) ? (sqrtf(acc2[r] / acc4[r]) * LOG2E) : 0.f;
    c2[r] = cr;
    cm2[r] = cr * mx[r];
  }

  // ---- PASS 2: split-bf16 scores -> w -> PV ----
  f32x4 pv[4];
#pragma unroll
  for (int dg = 0; dg < 4; ++dg) pv[dg] = fzero;
  float den[4] = {0, 0, 0, 0};
  bf16_t* wb = wbuf[wave];

  GLDS16(kh_b + lds_o, &kh_t[0][lds_o]);
  GLDS16(kl_b + lds_o, &kl_t[0][lds_o]);
  GLDS16(vt_b + lds_o, &v_t[0][lds_o]);
  for (int t = 0; t < 32; ++t) {
    __syncthreads();
    if (t < 31) {
      int go = (t + 1) * 2048 + lds_o;
      int bs = (t + 1) & 1;
      GLDS16(kh_b + go, &kh_t[bs][lds_o]);
      GLDS16(kl_b + go, &kl_t[bs][lds_o]);
      GLDS16(vt_b + go, &v_t[bs][lds_o]);
    }
    const bf16_t* kt = kh_t[t & 1];
    const bf16_t* lt = kl_t[t & 1];
    const bf16_t* vl = v_t[t & 1];
    f32x4 sc[2];
#pragma unroll
    for (int cg = 0; cg < 2; ++cg) {
      int ko = koff + cg * 1024;
      bf16x8 h0 = *(const bf16x8*)(kt + ko);
      bf16x8 h1 = *(const bf16x8*)(kt + (ko ^ 32));
      bf16x8 l0 = *(const bf16x8*)(lt + ko);
      bf16x8 l1 = *(const bf16x8*)(lt + (ko ^ 32));
      f32x4 s = fzero;
      // split product: qh*kh + qh*kl + ql*kh (ql*kl negligible)
      s = MFMA16(qah0, h0, s);
      s = MFMA16(qah1, h1, s);
      s = MFMA16(qah0, l0, s);
      s = MFMA16(qah1, l1, s);
      s = MFMA16(qal0, h0, s);
      s = MFMA16(qal1, h1, s);
      sc[cg] = s;
    }
    // w = 2^(c2*s^2 - c2*M); stash to per-wave LDS (C-layout -> A-layout)
#pragma unroll
    for (int cg = 0; cg < 2; ++cg)
#pragma unroll
      for (int r = 0; r < 4; ++r) {
        float s = sc[cg][r];
        float w = exp2f(fmaf(s * s, c2[r], -cm2[r]));
        den[r] += w;
        wb[(g * 4 + r) * 40 + cg * 16 + n] = (bf16_t)w;
      }
    bf16x8 wa = *(const bf16x8*)(wb + n * 40 + g * 8);  // same-wave, in-order
#pragma unroll
    for (int dg = 0; dg < 4; ++dg) {
      bf16x8 vb = *(const bf16x8*)(vl + n * 32 + dg * 512 + g * 8);
      pv[dg] = MFMA16(wa, vb, pv[dg]);
    }
  }
  // denominator reduce + normalize + store [B,L,H,D]
#pragma unroll
  for (int off = 1; off < 16; off <<= 1)
#pragma unroll
    for (int r = 0; r < 4; ++r) den[r] += __shfl_xor(den[r], off, 64);
#pragma unroll
  for (int r = 0; r < 4; ++r) {
    float inv = 1.f / den[r];
    int l = qb * 64 + wave * 16 + g * 4 + r;
    float* op = out + (((size_t)b * L_ + l) * H_ + h) * D_;
#pragma unroll
    for (int dg = 0; dg < 4; ++dg) op[dg * 16 + n] = pv[dg][r] * inv;
  }
}

extern "C" void kernel_launch(void* const* d_in, const int* in_sizes, int n_in,
                              void* d_out, int out_size, void* d_ws, size_t ws_size,
                              hipStream_t stream) {
  const float* q = (const float*)d_in[0];
  const float* k = (const float*)d_in[1];
  const float* v = (const float*)d_in[2];
  // d_in[3] (attn_mask) is all-False -> unused
  float* out = (float*)d_out;

  const size_t NE = (size_t)B_ * L_ * H_ * E_;  // 4,194,304 elems
  bf16_t* qh = (bf16_t*)d_ws;                   // ws usage: 5*NE*2B = 40 MB
  bf16_t* ql = qh + NE;
  bf16_t* kh = ql + NE;
  bf16_t* kl = kh + NE;
  bf16_t* vt = kl + NE;

  phi_kernel<<<(2 * B_ * L_ * H_) / 4, 256, 0, stream>>>(q, k, qh, ql, kh, kl);
  vt_kernel<<<BH_ * (S_ / 32), 256, 0, stream>>>(v, vt);
  attn_kernel<<<BH_ * (L_ / 64), 256, 0, stream>>>(qh, ql, kh, kl, vt, out);
}

// Round 3
// 198.020 us; speedup vs baseline: 1.0718x; 1.0165x over previous
//
#include <hip/hip_runtime.h>
#include <hip/hip_bf16.h>

// FocusAttention: B=8, L=S=1024, H=8, E=D=64
// qt = phi_p(q), kt = phi_p(k)  (power-norm p=2 over E)
// A = softmax(c * s^2) rowwise, c = sqrt(sum s^2 / sum s^4) (full-row const
// -> online softmax impossible; two passes over K, recompute QK^T in pass 2
// with split-bf16 hi+lo for score precision; see round-1 notes).
// out = A @ v, [B,L,H,D] fp32.
//
// R3: R2 counters: Occ 36, Mfma 21, VALU 41, FETCH 139MB vs ~34MB unique
// -> latency-bound with 4x L2 overfetch (16 q-blocks per bh scattered over
// all 8 XCDs) + 6-deep dependent MFMA chain in pass 2. Changes:
//  - XCD swizzle: bh = blockIdx&63 -> all q-blocks of a head on one XCD,
//    per-XCD K/V stream 3.6MB fits 4MB L2 -> B-frag feeds at ~200cy not 900
//  - score MFMAs restructured into independent chains (3x2 pass2, 4x1 pass1)

#define B_ 8
#define L_ 1024
#define H_ 8
#define E_ 64
#define S_ 1024
#define D_ 64
#define BH_ 64

typedef __bf16 bf16_t;
typedef __bf16 bf16x8 __attribute__((ext_vector_type(8)));
typedef float f32x4 __attribute__((ext_vector_type(4)));

#define MFMA16(a, b, c) __builtin_amdgcn_mfma_f32_16x16x32_bf16(a, b, c, 0, 0, 0)
#define GLDS16(g, l)                                                        \
  __builtin_amdgcn_global_load_lds(                                         \
      (const __attribute__((address_space(1))) void*)(g),                   \
      (__attribute__((address_space(3))) void*)(l), 16, 0, 0)

__device__ __forceinline__ float wave64_sum(float v) {
#pragma unroll
  for (int off = 32; off > 0; off >>= 1) v += __shfl_xor(v, off, 64);
  return v;
}

// ---------------------------------------------------------------------------
// K1: phi_p rows (one wave per 64-elem row) -> hi/lo bf16 in [B,H,row,E]
// with XOR chunk swizzle: chunk c (8 elems) stored at position c^(row&7).
// ---------------------------------------------------------------------------
__global__ __launch_bounds__(256) void phi_kernel(
    const float* __restrict__ q, const float* __restrict__ k,
    bf16_t* __restrict__ qh, bf16_t* __restrict__ ql,
    bf16_t* __restrict__ kh, bf16_t* __restrict__ kl) {
  int row = blockIdx.x * 4 + (threadIdx.x >> 6);
  int lane = threadIdx.x & 63;
  const float* src;
  bf16_t *dh, *dl;
  int r = row;
  if (r < B_ * L_ * H_) { src = q; dh = qh; dl = ql; }
  else { r -= B_ * L_ * H_; src = k; dh = kh; dl = kl; }
  int b = r >> 13;            // r / (L*H)
  int l = (r >> 3) & 1023;
  int h = r & 7;
  float x = src[(size_t)r * 64 + lane];
  float rl = fmaxf(x, 0.f);
  float s2 = rl * rl;
  float sum2 = wave64_sum(s2);
  float sum4 = wave64_sum(s2 * s2);
  float val = (sum4 > 0.f) ? (sqrtf(sum2 / sum4) * s2) : 0.f;
  bf16_t hi = (bf16_t)val;
  bf16_t lo = (bf16_t)(val - (float)hi);
  int c = lane >> 3, e = lane & 7;
  int col = ((c ^ (l & 7)) << 3) | e;  // swizzled chunk position
  size_t o = ((size_t)(b * H_ + h) * 1024 + l) * 64 + col;
  dh[o] = hi;
  dl[o] = lo;
}

// ---------------------------------------------------------------------------
// K1b: V [B,S,H,D] fp32 -> vt bf16 tiled [bh][st=S/32][64 d][32 s]
// (so attn's v staging is a contiguous 4KB block per tile)
// ---------------------------------------------------------------------------
__global__ __launch_bounds__(256) void vt_kernel(
    const float* __restrict__ v, bf16_t* __restrict__ vt) {
  __shared__ float tile[32][68];
  int bh = blockIdx.x >> 5;
  int st = blockIdx.x & 31;
  int b = bh >> 3, h = bh & 7;
  int t = threadIdx.x;
  int sl = t >> 3, dp = t & 7;
  const float* src = v + (((size_t)(b * S_ + st * 32 + sl) * H_ + h) * D_) + dp * 8;
  float4 f0 = ((const float4*)src)[0];
  float4 f1 = ((const float4*)src)[1];
  *(float4*)&tile[sl][dp * 8] = f0;
  *(float4*)&tile[sl][dp * 8 + 4] = f1;
  __syncthreads();
  int d = t >> 2, sc = t & 3;
  bf16_t tmp[8];
#pragma unroll
  for (int j = 0; j < 8; ++j) tmp[j] = (bf16_t)tile[sc * 8 + j][d];
  bf16_t* dst = vt + (((size_t)bh * 32 + st) * 64 + d) * 32 + sc * 8;
  *(uint4*)dst = *(const uint4*)tmp;
}

// ---------------------------------------------------------------------------
// K2: fused two-pass attention. Block = (b,h) x 64 q-rows; 4 waves x 16 rows.
// 32-row K tiles, double-buffered glds staging, 1 barrier/tile.
// Block decode XCD-swizzled: bh = idx&63 -> q-blocks of a head co-located.
// MFMA layouts (m89/m91): C/D col=lane&15, row=(lane>>4)*4+reg;
// A[m=lane&15][k=(lane>>4)*8+j]; B[k=(lane>>4)*8+j][n=lane&15].
// ---------------------------------------------------------------------------
__global__ __launch_bounds__(256, 4) void attn_kernel(
    const bf16_t* __restrict__ qh, const bf16_t* __restrict__ ql,
    const bf16_t* __restrict__ kh, const bf16_t* __restrict__ kl,
    const bf16_t* __restrict__ vt, float* __restrict__ out) {
  __shared__ __align__(16) bf16_t kh_t[2][2048];  // 32 s-rows x 64 e (swizzled)
  __shared__ __align__(16) bf16_t kl_t[2][2048];
  __shared__ __align__(16) bf16_t v_t[2][2048];   // 64 d-rows x 32 s (linear)
  __shared__ __align__(16) bf16_t wbuf[4][16 * 40];  // per-wave w, PAD 40

  int bh = blockIdx.x & 63;   // XCD swizzle: bh%8 == XCD for all its q-blocks
  int qb = blockIdx.x >> 6;
  int b = bh >> 3, h = bh & 7;
  int tid = threadIdx.x;
  int wave = tid >> 6, lane = tid & 63;
  int g = lane >> 4, n = lane & 15;

  const bf16_t* qh_b = qh + ((size_t)bh * L_ + qb * 64) * 64;
  const bf16_t* ql_b = ql + ((size_t)bh * L_ + qb * 64) * 64;
  const bf16_t* kh_b = kh + (size_t)bh * S_ * 64;
  const bf16_t* kl_b = kl + (size_t)bh * S_ * 64;
  const bf16_t* vt_b = vt + (size_t)bh * 32 * 2048;

  // Q A-fragments straight from global (swizzled chunk addressing).
  // chunk for k-step 0 is g, for k-step 1 is g+4 = g^4 -> offset ^32.
  int arow = wave * 16 + n;
  int qoff = arow * 64 + ((g ^ (n & 7)) << 3);
  bf16x8 qah0 = *(const bf16x8*)(qh_b + qoff);
  bf16x8 qah1 = *(const bf16x8*)(qh_b + (qoff ^ 32));
  bf16x8 qal0 = *(const bf16x8*)(ql_b + qoff);
  bf16x8 qal1 = *(const bf16x8*)(ql_b + (qoff ^ 32));

  // B-fragment base offset within a k tile (row n; row n+16 is +1024)
  int koff = n * 64 + ((g ^ (n & 7)) << 3);
  int lds_o = tid * 8;  // lane-linear staging slot (16B/thread)

  const f32x4 fzero = {0.f, 0.f, 0.f, 0.f};
  float acc2[4] = {0, 0, 0, 0}, acc4[4] = {0, 0, 0, 0}, mx[4] = {0, 0, 0, 0};

  // ---- PASS 1: row stats (single-bf16 scores suffice; c only shifts
  // near-tied exponents by ~1e-3, M cancels in softmax) ----
  GLDS16(kh_b + lds_o, &kh_t[0][lds_o]);
  for (int t = 0; t < 32; ++t) {
    __syncthreads();  // drains this wave's glds; barrier => tile t ready
    if (t < 31) GLDS16(kh_b + (t + 1) * 2048 + lds_o, &kh_t[(t + 1) & 1][lds_o]);
    const bf16_t* kt = kh_t[t & 1];
    bf16x8 b00 = *(const bf16x8*)(kt + koff);
    bf16x8 b01 = *(const bf16x8*)(kt + (koff ^ 32));
    bf16x8 b10 = *(const bf16x8*)(kt + koff + 1024);
    bf16x8 b11 = *(const bf16x8*)(kt + (koff ^ 32) + 1024);
    // 4 independent MFMAs (no C-chains) -> ILP; combine in fp32
    f32x4 p0 = MFMA16(qah0, b00, fzero);
    f32x4 p1 = MFMA16(qah1, b01, fzero);
    f32x4 p2 = MFMA16(qah0, b10, fzero);
    f32x4 p3 = MFMA16(qah1, b11, fzero);
    f32x4 sc0 = p0 + p1;
    f32x4 sc1 = p2 + p3;
#pragma unroll
    for (int r = 0; r < 4; ++r) {
      float s = sc0[r], s2 = s * s;
      acc2[r] += s2; acc4[r] = fmaf(s2, s2, acc4[r]); mx[r] = fmaxf(mx[r], s2);
      s = sc1[r]; s2 = s * s;
      acc2[r] += s2; acc4[r] = fmaf(s2, s2, acc4[r]); mx[r] = fmaxf(mx[r], s2);
    }
  }
#pragma unroll
  for (int off = 1; off < 16; off <<= 1)
#pragma unroll
    for (int r = 0; r < 4; ++r) {
      acc2[r] += __shfl_xor(acc2[r], off, 64);
      acc4[r] += __shfl_xor(acc4[r], off, 64);
      mx[r] = fmaxf(mx[r], __shfl_xor(mx[r], off, 64));
    }
  float c2[4], cm2[4];
  const float LOG2E = 1.44269504f;
#pragma unroll
  for (int r = 0; r < 4; ++r) {
    float cr = (acc4[r] > 0.f) ? (sqrtf(acc2[r] / acc4[r]) * LOG2E) : 0.f;
    c2[r] = cr;
    cm2[r] = cr * mx[r];
  }

  // ---- PASS 2: split-bf16 scores -> w -> PV ----
  f32x4 pv[4];
#pragma unroll
  for (int dg = 0; dg < 4; ++dg) pv[dg] = fzero;
  float den[4] = {0, 0, 0, 0};
  bf16_t* wb = wbuf[wave];

  GLDS16(kh_b + lds_o, &kh_t[0][lds_o]);
  GLDS16(kl_b + lds_o, &kl_t[0][lds_o]);
  GLDS16(vt_b + lds_o, &v_t[0][lds_o]);
  for (int t = 0; t < 32; ++t) {
    __syncthreads();
    if (t < 31) {
      int go = (t + 1) * 2048 + lds_o;
      int bs = (t + 1) & 1;
      GLDS16(kh_b + go, &kh_t[bs][lds_o]);
      GLDS16(kl_b + go, &kl_t[bs][lds_o]);
      GLDS16(vt_b + go, &v_t[bs][lds_o]);
    }
    const bf16_t* kt = kh_t[t & 1];
    const bf16_t* lt = kl_t[t & 1];
    const bf16_t* vl = v_t[t & 1];
    f32x4 sc[2];
#pragma unroll
    for (int cg = 0; cg < 2; ++cg) {
      int ko = koff + cg * 1024;
      bf16x8 h0 = *(const bf16x8*)(kt + ko);
      bf16x8 h1 = *(const bf16x8*)(kt + (ko ^ 32));
      bf16x8 l0 = *(const bf16x8*)(lt + ko);
      bf16x8 l1 = *(const bf16x8*)(lt + (ko ^ 32));
      // split product qh*kh + qh*kl + ql*kh as 3 independent 2-chains
      f32x4 sh = MFMA16(qah0, h0, fzero);
      sh = MFMA16(qah1, h1, sh);
      f32x4 sa = MFMA16(qah0, l0, fzero);
      sa = MFMA16(qah1, l1, sa);
      f32x4 sb = MFMA16(qal0, h0, fzero);
      sb = MFMA16(qal1, h1, sb);
      sc[cg] = (sh + sa) + sb;
    }
    // w = 2^(c2*s^2 - c2*M); stash to per-wave LDS (C-layout -> A-layout)
#pragma unroll
    for (int cg = 0; cg < 2; ++cg)
#pragma unroll
      for (int r = 0; r < 4; ++r) {
        float s = sc[cg][r];
        float w = exp2f(fmaf(s * s, c2[r], -cm2[r]));
        den[r] += w;
        wb[(g * 4 + r) * 40 + cg * 16 + n] = (bf16_t)w;
      }
    bf16x8 wa = *(const bf16x8*)(wb + n * 40 + g * 8);  // same-wave, in-order
#pragma unroll
    for (int dg = 0; dg < 4; ++dg) {
      bf16x8 vb = *(const bf16x8*)(vl + n * 32 + dg * 512 + g * 8);
      pv[dg] = MFMA16(wa, vb, pv[dg]);
    }
  }
  // denominator reduce + normalize + store [B,L,H,D]
#pragma unroll
  for (int off = 1; off < 16; off <<= 1)
#pragma unroll
    for (int r = 0; r < 4; ++r) den[r] += __shfl_xor(den[r], off, 64);
#pragma unroll
  for (int r = 0; r < 4; ++r) {
    float inv = 1.f / den[r];
    int l = qb * 64 + wave * 16 + g * 4 + r;
    float* op = out + (((size_t)b * L_ + l) * H_ + h) * D_;
#pragma unroll
    for (int dg = 0; dg < 4; ++dg) op[dg * 16 + n] = pv[dg][r] * inv;
  }
}

extern "C" void kernel_launch(void* const* d_in, const int* in_sizes, int n_in,
                              void* d_out, int out_size, void* d_ws, size_t ws_size,
                              hipStream_t stream) {
  const float* q = (const float*)d_in[0];
  const float* k = (const float*)d_in[1];
  const float* v = (const float*)d_in[2];
  // d_in[3] (attn_mask) is all-False -> unused
  float* out = (float*)d_out;

  const size_t NE = (size_t)B_ * L_ * H_ * E_;  // 4,194,304 elems
  bf16_t* qh = (bf16_t*)d_ws;                   // ws usage: 5*NE*2B = 40 MB
  bf16_t* ql = qh + NE;
  bf16_t* kh = ql + NE;
  bf16_t* kl = kh + NE;
  bf16_t* vt = kl + NE;

  phi_kernel<<<(2 * B_ * L_ * H_) / 4, 256, 0, stream>>>(q, k, qh, ql, kh, kl);
  vt_kernel<<<BH_ * (S_ / 32), 256, 0, stream>>>(v, vt);
  attn_kernel<<<BH_ * (L_ / 64), 256, 0, stream>>>(qh, ql, kh, kl, vt, out);
}

// Round 4
// 183.251 us; speedup vs baseline: 1.1582x; 1.0806x over previous
//
#include <hip/hip_runtime.h>
#include <hip/hip_bf16.h>

// FocusAttention: B=8, L=S=1024, H=8, E=D=64
// qt = phi_p(q), kt = phi_p(k)  (power-norm p=2 over E)
// A = softmax(c * s^2) rowwise, c = sqrt(sum s^2 / sum s^4) (full-row const
// -> online softmax impossible; two passes over K, recompute QK^T in pass 2).
// out = A @ v, [B,L,H,D] fp32.
//
// R4: problem shape caps TLP at 4 waves/SIMD (4096 waves total) -> cut
// per-tile work instead of chasing occupancy.
//  - fp16 operands everywhere (error analysis: score noise 2e-4*s ->
//    exponent noise ~0.02 -> absmax ~0.04 < 0.095). Kills the bf16 hi/lo
//    split: pass-2 score MFMAs 12->4, LDS reads 8->4, kl/ql arrays gone.
//  - pass 1 reads K B-frags DIRECT FROM GLOBAL (L2-resident after XCD
//    swizzle, ~200cy) -> zero barriers in pass 1, compiler pipelines.
//  - XCD swizzle kept (R3: FETCH 139->25MB), XOR chunk swizzle kept.

#define B_ 8
#define L_ 1024
#define H_ 8
#define E_ 64
#define S_ 1024
#define D_ 64
#define BH_ 64

typedef _Float16 f16_t;
typedef _Float16 f16x8 __attribute__((ext_vector_type(8)));
typedef float f32x4 __attribute__((ext_vector_type(4)));

#define MFMA16F(a, b, c) __builtin_amdgcn_mfma_f32_16x16x32_f16(a, b, c, 0, 0, 0)
#define GLDS16(g, l)                                                        \
  __builtin_amdgcn_global_load_lds(                                         \
      (const __attribute__((address_space(1))) void*)(g),                   \
      (__attribute__((address_space(3))) void*)(l), 16, 0, 0)

__device__ __forceinline__ float wave64_sum(float v) {
#pragma unroll
  for (int off = 32; off > 0; off >>= 1) v += __shfl_xor(v, off, 64);
  return v;
}

// ---------------------------------------------------------------------------
// K1: phi_p rows (one wave per 64-elem row) -> f16 in [B,H,row,E] with XOR
// chunk swizzle: chunk c (8 elems) stored at position c^(row&7).
// ---------------------------------------------------------------------------
__global__ __launch_bounds__(256) void phi_kernel(
    const float* __restrict__ q, const float* __restrict__ k,
    f16_t* __restrict__ qf, f16_t* __restrict__ kf) {
  int row = blockIdx.x * 4 + (threadIdx.x >> 6);
  int lane = threadIdx.x & 63;
  const float* src;
  f16_t* dst;
  int r = row;
  if (r < B_ * L_ * H_) { src = q; dst = qf; }
  else { r -= B_ * L_ * H_; src = k; dst = kf; }
  int b = r >> 13;            // r / (L*H)
  int l = (r >> 3) & 1023;
  int h = r & 7;
  float x = src[(size_t)r * 64 + lane];
  float rl = fmaxf(x, 0.f);
  float s2 = rl * rl;
  float sum2 = wave64_sum(s2);
  float sum4 = wave64_sum(s2 * s2);
  float val = (sum4 > 0.f) ? (sqrtf(sum2 / sum4) * s2) : 0.f;
  int c = lane >> 3, e = lane & 7;
  int col = ((c ^ (l & 7)) << 3) | e;  // swizzled chunk position
  size_t o = ((size_t)(b * H_ + h) * 1024 + l) * 64 + col;
  dst[o] = (f16_t)val;
}

// ---------------------------------------------------------------------------
// K1b: V [B,S,H,D] fp32 -> vt f16 tiled [bh][st=S/32][64 d][32 s]
// (attn's v staging = contiguous 4KB block per tile)
// ---------------------------------------------------------------------------
__global__ __launch_bounds__(256) void vt_kernel(
    const float* __restrict__ v, f16_t* __restrict__ vt) {
  __shared__ float tile[32][68];
  int bh = blockIdx.x >> 5;
  int st = blockIdx.x & 31;
  int b = bh >> 3, h = bh & 7;
  int t = threadIdx.x;
  int sl = t >> 3, dp = t & 7;
  const float* src = v + (((size_t)(b * S_ + st * 32 + sl) * H_ + h) * D_) + dp * 8;
  float4 f0 = ((const float4*)src)[0];
  float4 f1 = ((const float4*)src)[1];
  *(float4*)&tile[sl][dp * 8] = f0;
  *(float4*)&tile[sl][dp * 8 + 4] = f1;
  __syncthreads();
  int d = t >> 2, sc = t & 3;
  f16_t tmp[8];
#pragma unroll
  for (int j = 0; j < 8; ++j) tmp[j] = (f16_t)tile[sc * 8 + j][d];
  f16_t* dst = vt + (((size_t)bh * 32 + st) * 64 + d) * 32 + sc * 8;
  *(uint4*)dst = *(const uint4*)tmp;
}

// ---------------------------------------------------------------------------
// K2: fused two-pass attention. Block = (b,h) x 64 q-rows; 4 waves x 16 rows.
// Pass 1: barrier-free, K B-frags direct from global (L2).
// Pass 2: 32-row K+V tiles, double-buffered glds, 1 barrier/tile.
// MFMA layouts (m89/m91): C/D col=lane&15, row=(lane>>4)*4+reg;
// A[m=lane&15][k=(lane>>4)*8+j]; B[k=(lane>>4)*8+j][n=lane&15].
// ---------------------------------------------------------------------------
__global__ __launch_bounds__(256, 4) void attn_kernel(
    const f16_t* __restrict__ qf, const f16_t* __restrict__ kf,
    const f16_t* __restrict__ vt, float* __restrict__ out) {
  __shared__ __align__(16) f16_t k_t[2][2048];   // 32 s-rows x 64 e (swizzled)
  __shared__ __align__(16) f16_t v_t[2][2048];   // 64 d-rows x 32 s (linear)
  __shared__ __align__(16) f16_t wbuf[4][16 * 40];  // per-wave w, PAD 40

  int bh = blockIdx.x & 63;   // XCD swizzle: all q-blocks of a head co-located
  int qb = blockIdx.x >> 6;
  int b = bh >> 3, h = bh & 7;
  int tid = threadIdx.x;
  int wave = tid >> 6, lane = tid & 63;
  int g = lane >> 4, n = lane & 15;

  const f16_t* qf_b = qf + ((size_t)bh * L_ + qb * 64) * 64;
  const f16_t* kf_b = kf + (size_t)bh * S_ * 64;
  const f16_t* vt_b = vt + (size_t)bh * 32 * 2048;

  // Q A-fragments from global (swizzled chunk addressing);
  // k-step 0 chunk g, k-step 1 chunk g^4 -> element offset ^32.
  int arow = wave * 16 + n;
  int qoff = arow * 64 + ((g ^ (n & 7)) << 3);
  f16x8 qa0 = *(const f16x8*)(qf_b + qoff);
  f16x8 qa1 = *(const f16x8*)(qf_b + (qoff ^ 32));

  // B-fragment offset within a K tile (row n; row n+16 at +1024)
  int koff = n * 64 + ((g ^ (n & 7)) << 3);
  int lds_o = tid * 8;  // lane-linear staging slot (16B/thread)

  const f32x4 fzero = {0.f, 0.f, 0.f, 0.f};
  float acc2[4] = {0, 0, 0, 0}, acc4[4] = {0, 0, 0, 0}, mx[4] = {0, 0, 0, 0};

  // ---- PASS 1: row stats, barrier-free (K read direct from global/L2) ----
#pragma unroll 2
  for (int t = 0; t < 32; ++t) {
    const f16_t* kg = kf_b + t * 2048;
    f16x8 b00 = *(const f16x8*)(kg + koff);
    f16x8 b01 = *(const f16x8*)(kg + (koff ^ 32));
    f16x8 b10 = *(const f16x8*)(kg + koff + 1024);
    f16x8 b11 = *(const f16x8*)(kg + (koff ^ 32) + 1024);
    f32x4 sc0 = MFMA16F(qa0, b00, fzero);
    sc0 = MFMA16F(qa1, b01, sc0);
    f32x4 sc1 = MFMA16F(qa0, b10, fzero);
    sc1 = MFMA16F(qa1, b11, sc1);
#pragma unroll
    for (int r = 0; r < 4; ++r) {
      float s = sc0[r], s2 = s * s;
      acc2[r] += s2; acc4[r] = fmaf(s2, s2, acc4[r]); mx[r] = fmaxf(mx[r], s2);
      s = sc1[r]; s2 = s * s;
      acc2[r] += s2; acc4[r] = fmaf(s2, s2, acc4[r]); mx[r] = fmaxf(mx[r], s2);
    }
  }
#pragma unroll
  for (int off = 1; off < 16; off <<= 1)
#pragma unroll
    for (int r = 0; r < 4; ++r) {
      acc2[r] += __shfl_xor(acc2[r], off, 64);
      acc4[r] += __shfl_xor(acc4[r], off, 64);
      mx[r] = fmaxf(mx[r], __shfl_xor(mx[r], off, 64));
    }
  float c2[4], cm2[4];
  const float LOG2E = 1.44269504f;
#pragma unroll
  for (int r = 0; r < 4; ++r) {
    float cr = (acc4[r] > 0.f) ? (sqrtf(acc2[r] / acc4[r]) * LOG2E) : 0.f;
    c2[r] = cr;
    cm2[r] = cr * mx[r];
  }

  // ---- PASS 2: fp16 scores -> w -> PV (glds + 1 barrier/tile) ----
  f32x4 pv[4];
#pragma unroll
  for (int dg = 0; dg < 4; ++dg) pv[dg] = fzero;
  float den[4] = {0, 0, 0, 0};
  f16_t* wb = wbuf[wave];

  GLDS16(kf_b + lds_o, &k_t[0][lds_o]);
  GLDS16(vt_b + lds_o, &v_t[0][lds_o]);
  for (int t = 0; t < 32; ++t) {
    __syncthreads();  // drains glds -> tile t ready
    if (t < 31) {
      int go = (t + 1) * 2048 + lds_o;
      int bs = (t + 1) & 1;
      GLDS16(kf_b + go, &k_t[bs][lds_o]);
      GLDS16(vt_b + go, &v_t[bs][lds_o]);
    }
    const f16_t* kt = k_t[t & 1];
    const f16_t* vl = v_t[t & 1];
    // V B-frags issued early (independent of score chain)
    f16x8 vb[4];
#pragma unroll
    for (int dg = 0; dg < 4; ++dg)
      vb[dg] = *(const f16x8*)(vl + n * 32 + dg * 512 + g * 8);
    f16x8 b00 = *(const f16x8*)(kt + koff);
    f16x8 b01 = *(const f16x8*)(kt + (koff ^ 32));
    f16x8 b10 = *(const f16x8*)(kt + koff + 1024);
    f16x8 b11 = *(const f16x8*)(kt + (koff ^ 32) + 1024);
    f32x4 sc0 = MFMA16F(qa0, b00, fzero);
    sc0 = MFMA16F(qa1, b01, sc0);
    f32x4 sc1 = MFMA16F(qa0, b10, fzero);
    sc1 = MFMA16F(qa1, b11, sc1);
    // w = 2^(c2*s^2 - c2*M); C-layout -> A-layout via per-wave LDS
#pragma unroll
    for (int r = 0; r < 4; ++r) {
      float w0 = exp2f(fmaf(sc0[r] * sc0[r], c2[r], -cm2[r]));
      float w1 = exp2f(fmaf(sc1[r] * sc1[r], c2[r], -cm2[r]));
      den[r] += w0 + w1;
      wb[(g * 4 + r) * 40 + n] = (f16_t)w0;
      wb[(g * 4 + r) * 40 + 16 + n] = (f16_t)w1;
    }
    f16x8 wa = *(const f16x8*)(wb + n * 40 + g * 8);  // same-wave, in-order
#pragma unroll
    for (int dg = 0; dg < 4; ++dg) pv[dg] = MFMA16F(wa, vb[dg], pv[dg]);
  }
  // denominator reduce + normalize + store [B,L,H,D]
#pragma unroll
  for (int off = 1; off < 16; off <<= 1)
#pragma unroll
    for (int r = 0; r < 4; ++r) den[r] += __shfl_xor(den[r], off, 64);
#pragma unroll
  for (int r = 0; r < 4; ++r) {
    float inv = 1.f / den[r];
    int l = qb * 64 + wave * 16 + g * 4 + r;
    float* op = out + (((size_t)b * L_ + l) * H_ + h) * D_;
#pragma unroll
    for (int dg = 0; dg < 4; ++dg) op[dg * 16 + n] = pv[dg][r] * inv;
  }
}

extern "C" void kernel_launch(void* const* d_in, const int* in_sizes, int n_in,
                              void* d_out, int out_size, void* d_ws, size_t ws_size,
                              hipStream_t stream) {
  const float* q = (const float*)d_in[0];
  const float* k = (const float*)d_in[1];
  const float* v = (const float*)d_in[2];
  // d_in[3] (attn_mask) is all-False -> unused
  float* out = (float*)d_out;

  const size_t NE = (size_t)B_ * L_ * H_ * E_;  // 4,194,304 elems
  f16_t* qf = (f16_t*)d_ws;                     // ws usage: 3*NE*2B = 24 MB
  f16_t* kf = qf + NE;
  f16_t* vt = kf + NE;

  phi_kernel<<<(2 * B_ * L_ * H_) / 4, 256, 0, stream>>>(q, k, qf, kf);
  vt_kernel<<<BH_ * (S_ / 32), 256, 0, stream>>>(v, vt);
  attn_kernel<<<BH_ * (L_ / 64), 256, 0, stream>>>(qf, kf, vt, out);
}